// Round 1
// baseline (710.399 us; speedup 1.0000x reference)
//
#include <hip/hip_runtime.h>
#include <hip/hip_bf16.h>

#define NEG_SLOPE 0.2f

// ---------------------------------------------------------------- CSR build
__global__ void hist_kernel(const int* __restrict__ dst, int* __restrict__ counts, int E) {
    int e = blockIdx.x * blockDim.x + threadIdx.x;
    if (e < E) atomicAdd(&counts[dst[e]], 1);
}

// single-block exclusive scan: counts[N] -> row_ptr[N+1]
__global__ void scan_kernel(const int* __restrict__ counts, int* __restrict__ row_ptr, int N) {
    __shared__ int wsum[16];
    __shared__ int carry_s;
    int tid = threadIdx.x, lane = tid & 63, wid = tid >> 6;
    if (tid == 0) carry_s = 0;
    __syncthreads();
    for (int base = 0; base < N; base += 1024) {
        int i = base + tid;
        int v = (i < N) ? counts[i] : 0;
        // inclusive wave scan
        int x = v;
        #pragma unroll
        for (int off = 1; off < 64; off <<= 1) {
            int t = __shfl_up(x, off);
            if (lane >= off) x += t;
        }
        if (lane == 63) wsum[wid] = x;
        __syncthreads();
        if (wid == 0 && lane < 16) {
            int w = wsum[lane];
            int inc = w;
            #pragma unroll
            for (int off = 1; off < 16; off <<= 1) {
                int t = __shfl_up(inc, off);
                if (lane >= off) inc += t;
            }
            wsum[lane] = inc - w;   // exclusive prefix of wave totals
        }
        __syncthreads();
        int excl = carry_s + wsum[wid] + x - v;
        if (i < N) row_ptr[i] = excl;
        __syncthreads();
        if (tid == 1023) carry_s += wsum[15] + x;  // x(tid1023) = wave15 inclusive total
        __syncthreads();
    }
    if (threadIdx.x == 0) row_ptr[N] = carry_s;
}

__global__ void scatter_kernel(const int* __restrict__ src, const int* __restrict__ dst,
                               const int* __restrict__ row_ptr, int* __restrict__ cursor,
                               int* __restrict__ col_src, int E) {
    int e = blockIdx.x * blockDim.x + threadIdx.x;
    if (e < E) {
        int d = dst[e];
        int pos = atomicAdd(&cursor[d], 1);
        col_src[row_ptr[d] + pos] = src[e];
    }
}

// ---------------------------------------------------------------- GEMM (fp32)
// out[n,c] = sum_k X[n,k] * W[k,c].  W fully staged in LDS, X tile padded.
template<int FIN, int FOUT, int ROWS>
__global__ __launch_bounds__(256) void gemm_kernel(const float* __restrict__ X,
                                                   const float* __restrict__ W,
                                                   float* __restrict__ Hout, int N) {
    constexpr int TPR = 256 / ROWS;     // threads per row
    constexpr int CPT = FOUT / TPR;     // cols per thread
    constexpr int NG  = CPT / 4;        // float4 groups per thread
    constexpr int XS  = FIN + 4;        // padded X stride (bank spread)
    static_assert(CPT % 4 == 0, "CPT must be multiple of 4");
    __shared__ float sW[FIN * FOUT];
    __shared__ float sX[ROWS * XS];
    int tid = threadIdx.x;
    for (int i = tid * 4; i < FIN * FOUT; i += 1024)
        *(float4*)&sW[i] = *(const float4*)&W[i];
    int row0 = blockIdx.x * ROWS;
    for (int i = tid * 4; i < ROWS * FIN; i += 1024) {
        int r = i / FIN, k = i % FIN;
        int gr = row0 + r;
        float4 v = make_float4(0.f, 0.f, 0.f, 0.f);
        if (gr < N) v = *(const float4*)&X[(size_t)gr * FIN + k];
        *(float4*)&sX[r * XS + k] = v;
    }
    __syncthreads();
    int r  = tid / TPR;
    int cb = (tid % TPR) * 4;           // base col; groups at stride TPR*4
    float4 acc[NG];
    #pragma unroll
    for (int g = 0; g < NG; ++g) acc[g] = make_float4(0.f, 0.f, 0.f, 0.f);
    const float* xrow = &sX[r * XS];
    for (int k = 0; k < FIN; ++k) {
        float xv = xrow[k];
        #pragma unroll
        for (int g = 0; g < NG; ++g) {
            float4 w = *(const float4*)&sW[k * FOUT + cb + g * (TPR * 4)];
            acc[g].x += xv * w.x; acc[g].y += xv * w.y;
            acc[g].z += xv * w.z; acc[g].w += xv * w.w;
        }
    }
    int gr = row0 + r;
    if (gr < N) {
        #pragma unroll
        for (int g = 0; g < NG; ++g)
            *(float4*)&Hout[(size_t)gr * FOUT + cb + g * (TPR * 4)] = acc[g];
    }
}

// small layer-3 GEMM: [N,64] @ [64,2]
__global__ void gemm3_kernel(const float* __restrict__ X, const float* __restrict__ W,
                             float* __restrict__ Hout, int N) {
    int n = blockIdx.x * blockDim.x + threadIdx.x;
    if (n >= N) return;
    float a0 = 0.f, a1 = 0.f;
    const float4* xr = (const float4*)(X + (size_t)n * 64);
    #pragma unroll
    for (int k4 = 0; k4 < 16; ++k4) {
        float4 x = xr[k4];
        int k = k4 * 4;
        a0 += x.x * W[(k + 0) * 2] + x.y * W[(k + 1) * 2] + x.z * W[(k + 2) * 2] + x.w * W[(k + 3) * 2];
        a1 += x.x * W[(k + 0) * 2 + 1] + x.y * W[(k + 1) * 2 + 1] + x.z * W[(k + 2) * 2 + 1] + x.w * W[(k + 3) * 2 + 1];
    }
    Hout[n * 2 + 0] = a0;
    Hout[n * 2 + 1] = a1;
}

// ---------------------------------------------------------------- attention dots
// a_src[n,h] = sum_c h[n,h*C+c]*att_s[h,c]; same for a_dst
template<int H, int C>
__global__ void attn_kernel(const float* __restrict__ Hm, const float* __restrict__ att_s,
                            const float* __restrict__ att_d, float* __restrict__ a_src,
                            float* __restrict__ a_dst, int N) {
    int t = blockIdx.x * blockDim.x + threadIdx.x;
    int n = t / H, h = t % H;
    if (n >= N) return;
    const float* row = Hm + (size_t)n * H * C + h * C;
    float as = 0.f, ad = 0.f;
    if constexpr (C % 4 == 0) {
        for (int c = 0; c < C; c += 4) {
            float4 v = *(const float4*)&row[c];
            float4 s = *(const float4*)&att_s[h * C + c];
            float4 d = *(const float4*)&att_d[h * C + c];
            as += v.x * s.x + v.y * s.y + v.z * s.z + v.w * s.w;
            ad += v.x * d.x + v.y * d.y + v.z * d.z + v.w * d.w;
        }
    } else {
        for (int c = 0; c < C; ++c) {
            float v = row[c];
            as += v * att_s[h * C + c];
            ad += v * att_d[h * C + c];
        }
    }
    a_src[n * H + h] = as;
    a_dst[n * H + h] = ad;
}

// ---------------------------------------------------------------- aggregation
// one wave per dst node: online softmax over incoming edges (+ virtual self-loop),
// then channel-parallel weighted gather-accumulate. bias + optional ELU fused.
template<int H, int C, bool ELU>
__global__ __launch_bounds__(256) void agg_kernel(
        const float* __restrict__ Hm, const float* __restrict__ a_src,
        const float* __restrict__ a_dst, const int* __restrict__ row_ptr,
        const int* __restrict__ col_src, const float* __restrict__ bias,
        float* __restrict__ out, int N) {
    constexpr int HC  = H * C;
    constexpr int EPL = (HC + 63) / 64;  // elements per lane
    int wave = (int)((blockIdx.x * blockDim.x + threadIdx.x) >> 6);
    int lane = threadIdx.x & 63;
    if (wave >= N) return;
    int n = wave;
    int start = row_ptr[n];
    int deg   = row_ptr[n + 1] - start;
    float adv[H];
    #pragma unroll
    for (int h = 0; h < H; ++h) adv[h] = a_dst[n * H + h];
    // pass 1: per-lane online max/sum per head over edges (i==deg is the self-loop)
    float m[H], s[H];
    #pragma unroll
    for (int h = 0; h < H; ++h) { m[h] = -1e30f; s[h] = 0.f; }
    for (int i = lane; i <= deg; i += 64) {
        int src = (i < deg) ? col_src[start + i] : n;
        #pragma unroll
        for (int h = 0; h < H; ++h) {
            float e = a_src[src * H + h] + adv[h];
            e = (e >= 0.f) ? e : NEG_SLOPE * e;
            if (e > m[h]) {
                s[h] = s[h] * __expf(m[h] - e) + 1.f;
                m[h] = e;
            } else {
                s[h] += __expf(e - m[h]);
            }
        }
    }
    #pragma unroll
    for (int off = 32; off; off >>= 1) {
        #pragma unroll
        for (int h = 0; h < H; ++h) {
            float m2 = __shfl_xor(m[h], off);
            float s2 = __shfl_xor(s[h], off);
            float nm = fmaxf(m[h], m2);
            s[h] = s[h] * __expf(m[h] - nm) + s2 * __expf(m2 - nm);
            m[h] = nm;
        }
    }
    float inv_s[H];
    #pragma unroll
    for (int h = 0; h < H; ++h) inv_s[h] = 1.f / s[h];
    // pass 2: weighted gather; lane owns elements lane + j*64
    float acc[EPL];
    #pragma unroll
    for (int j = 0; j < EPL; ++j) acc[j] = 0.f;
    for (int i = 0; i <= deg; ++i) {
        int src = (i < deg) ? col_src[start + i] : n;
        const float* hrow = Hm + (size_t)src * HC;
        #pragma unroll
        for (int j = 0; j < EPL; ++j) {
            int elem = lane + j * 64;
            if (HC % 64 == 0 || elem < HC) {
                int hh = elem / C;
                float e = a_src[src * H + hh] + adv[hh];
                e = (e >= 0.f) ? e : NEG_SLOPE * e;
                float w = __expf(e - m[hh]) * inv_s[hh];
                acc[j] += w * hrow[elem];
            }
        }
    }
    #pragma unroll
    for (int j = 0; j < EPL; ++j) {
        int elem = lane + j * 64;
        if (HC % 64 == 0 || elem < HC) {
            float v = acc[j] + bias[elem];
            if (ELU) v = (v > 0.f) ? v : __expf(v) - 1.f;
            out[(size_t)n * HC + elem] = v;
        }
    }
}

// layer 3: H=1, C=2, fused online-softmax aggregation + bias + log_softmax -> d_out
__global__ __launch_bounds__(256) void agg3_kernel(
        const float* __restrict__ Hm, const float* __restrict__ a_src,
        const float* __restrict__ a_dst, const int* __restrict__ row_ptr,
        const int* __restrict__ col_src, const float* __restrict__ bias,
        float* __restrict__ out, int N) {
    int wave = (int)((blockIdx.x * blockDim.x + threadIdx.x) >> 6);
    int lane = threadIdx.x & 63;
    if (wave >= N) return;
    int n = wave;
    int start = row_ptr[n];
    int deg   = row_ptr[n + 1] - start;
    float adv = a_dst[n];
    float m = -1e30f, s = 0.f, acc0 = 0.f, acc1 = 0.f;
    for (int i = lane; i <= deg; i += 64) {
        int src = (i < deg) ? col_src[start + i] : n;
        float e = a_src[src] + adv;
        e = (e >= 0.f) ? e : NEG_SLOPE * e;
        float h0 = Hm[src * 2], h1 = Hm[src * 2 + 1];
        if (e > m) {
            float c = __expf(m - e);
            s = s * c + 1.f; acc0 = acc0 * c + h0; acc1 = acc1 * c + h1;
            m = e;
        } else {
            float p = __expf(e - m);
            s += p; acc0 += p * h0; acc1 += p * h1;
        }
    }
    #pragma unroll
    for (int off = 32; off; off >>= 1) {
        float m2  = __shfl_xor(m, off);
        float s2  = __shfl_xor(s, off);
        float a02 = __shfl_xor(acc0, off);
        float a12 = __shfl_xor(acc1, off);
        float nm = fmaxf(m, m2);
        float c1 = __expf(m - nm), c2 = __expf(m2 - nm);
        s = s * c1 + s2 * c2; acc0 = acc0 * c1 + a02 * c2; acc1 = acc1 * c1 + a12 * c2;
        m = nm;
    }
    if (lane == 0) {
        float v0 = acc0 / s + bias[0];
        float v1 = acc1 / s + bias[1];
        float mx = fmaxf(v0, v1);
        float lse = mx + logf(__expf(v0 - mx) + __expf(v1 - mx));
        out[n * 2 + 0] = v0 - lse;
        out[n * 2 + 1] = v1 - lse;
    }
}

// ---------------------------------------------------------------- launch
extern "C" void kernel_launch(void* const* d_in, const int* in_sizes, int n_in,
                              void* d_out, int out_size, void* d_ws, size_t ws_size,
                              hipStream_t stream) {
    const float* x   = (const float*)d_in[0];
    const int*   ei  = (const int*)d_in[1];
    const float* W1  = (const float*)d_in[2];
    const float* as1 = (const float*)d_in[3];
    const float* ad1 = (const float*)d_in[4];
    const float* b1  = (const float*)d_in[5];
    const float* W2  = (const float*)d_in[6];
    const float* as2 = (const float*)d_in[7];
    const float* ad2 = (const float*)d_in[8];
    const float* b2  = (const float*)d_in[9];
    const float* W3  = (const float*)d_in[10];
    const float* as3 = (const float*)d_in[11];
    const float* ad3 = (const float*)d_in[12];
    const float* b3  = (const float*)d_in[13];
    int N = in_sizes[0] / 128;
    int E = in_sizes[1] / 2;
    const int* src = ei;
    const int* dst = ei + E;

    char* ws = (char*)d_ws;
    size_t off = 0;
    auto alloc = [&](size_t bytes) -> void* {
        void* p = ws + off;
        off = (off + bytes + 255) & ~(size_t)255;
        return p;
    };
    int*   row_ptr = (int*)alloc((size_t)(N + 1) * 4);
    int*   cursor  = (int*)alloc((size_t)N * 4);
    int*   col_src = (int*)alloc((size_t)E * 4);
    float* hbuf    = (float*)alloc((size_t)N * 128 * 4);
    float* obuf    = (float*)alloc((size_t)N * 128 * 4);
    float* asrc    = (float*)alloc((size_t)N * 4 * 4);
    float* adst    = (float*)alloc((size_t)N * 4 * 4);

    // CSR by dst
    hipMemsetAsync(cursor, 0, (size_t)N * 4, stream);
    hist_kernel<<<(E + 255) / 256, 256, 0, stream>>>(dst, cursor, E);
    scan_kernel<<<1, 1024, 0, stream>>>(cursor, row_ptr, N);
    hipMemsetAsync(cursor, 0, (size_t)N * 4, stream);
    scatter_kernel<<<(E + 255) / 256, 256, 0, stream>>>(src, dst, row_ptr, cursor, col_src, E);

    // layer 1: 128 -> 4x32 (concat), elu
    gemm_kernel<128, 128, 16><<<(N + 15) / 16, 256, 0, stream>>>(x, W1, hbuf, N);
    attn_kernel<4, 32><<<(N * 4 + 255) / 256, 256, 0, stream>>>(hbuf, as1, ad1, asrc, adst, N);
    agg_kernel<4, 32, true><<<(N + 3) / 4, 256, 0, stream>>>(hbuf, asrc, adst, row_ptr, col_src, b1, obuf, N);

    // layer 2: 128 -> 2x32 (concat), elu
    gemm_kernel<128, 64, 16><<<(N + 15) / 16, 256, 0, stream>>>(obuf, W2, hbuf, N);
    attn_kernel<2, 32><<<(N * 2 + 255) / 256, 256, 0, stream>>>(hbuf, as2, ad2, asrc, adst, N);
    agg_kernel<2, 32, true><<<(N + 3) / 4, 256, 0, stream>>>(hbuf, asrc, adst, row_ptr, col_src, b2, obuf, N);

    // layer 3: 64 -> 2, mean over 1 head, bias, log_softmax
    gemm3_kernel<<<(N + 255) / 256, 256, 0, stream>>>(obuf, W3, hbuf, N);
    attn_kernel<1, 2><<<(N + 255) / 256, 256, 0, stream>>>(hbuf, as3, ad3, asrc, adst, N);
    agg3_kernel<<<(N + 3) / 4, 256, 0, stream>>>(hbuf, asrc, adst, row_ptr, col_src, b3, (float*)d_out, N);
}

// Round 2
// 526.018 us; speedup vs baseline: 1.3505x; 1.3505x over previous
//
#include <hip/hip_runtime.h>
#include <hip/hip_bf16.h>

#define NEG_SLOPE 0.2f

// ---------------------------------------------------------------- bf16 helpers
__device__ __forceinline__ float bf_lo(uint32_t u) { return __uint_as_float(u << 16); }
__device__ __forceinline__ float bf_hi(uint32_t u) { return __uint_as_float(u & 0xffff0000u); }
__device__ __forceinline__ unsigned short f2bf(float f) {
    uint32_t u = __float_as_uint(f);
    u += 0x7fffu + ((u >> 16) & 1u);   // round-to-nearest-even
    return (unsigned short)(u >> 16);
}

// ---------------------------------------------------------------- CSR build
__global__ void hist_kernel(const int* __restrict__ dst, int* __restrict__ counts, int E) {
    int e = blockIdx.x * blockDim.x + threadIdx.x;
    if (e < E) atomicAdd(&counts[dst[e]], 1);
}

// single-block exclusive scan: counts[N] -> row_ptr[N+1]
__global__ void scan_kernel(const int* __restrict__ counts, int* __restrict__ row_ptr, int N) {
    __shared__ int wsum[16];
    __shared__ int carry_s;
    int tid = threadIdx.x, lane = tid & 63, wid = tid >> 6;
    if (tid == 0) carry_s = 0;
    __syncthreads();
    for (int base = 0; base < N; base += 1024) {
        int i = base + tid;
        int v = (i < N) ? counts[i] : 0;
        int x = v;
        #pragma unroll
        for (int off = 1; off < 64; off <<= 1) {
            int t = __shfl_up(x, off);
            if (lane >= off) x += t;
        }
        if (lane == 63) wsum[wid] = x;
        __syncthreads();
        if (wid == 0 && lane < 16) {
            int w = wsum[lane];
            int inc = w;
            #pragma unroll
            for (int off = 1; off < 16; off <<= 1) {
                int t = __shfl_up(inc, off);
                if (lane >= off) inc += t;
            }
            wsum[lane] = inc - w;
        }
        __syncthreads();
        int excl = carry_s + wsum[wid] + x - v;
        if (i < N) row_ptr[i] = excl;
        __syncthreads();
        if (tid == 1023) carry_s += wsum[15] + x;
        __syncthreads();
    }
    if (threadIdx.x == 0) row_ptr[N] = carry_s;
}

__global__ void scatter_kernel(const int* __restrict__ src, const int* __restrict__ dst,
                               const int* __restrict__ row_ptr, int* __restrict__ cursor,
                               int* __restrict__ col_src, int E) {
    int e = blockIdx.x * blockDim.x + threadIdx.x;
    if (e < E) {
        int d = dst[e];
        int pos = atomicAdd(&cursor[d], 1);
        col_src[row_ptr[d] + pos] = src[e];
    }
}

// ---------------------------------------------------------------- GEMM (fp32 in, fp32 or bf16 out)
template<int FIN, int FOUT, int ROWS, bool BF16OUT>
__global__ __launch_bounds__(256) void gemm_kernel(const float* __restrict__ X,
                                                   const float* __restrict__ W,
                                                   void* __restrict__ Hout, int N) {
    constexpr int TPR = 256 / ROWS;
    constexpr int CPT = FOUT / TPR;
    constexpr int NG  = CPT / 4;
    constexpr int XS  = FIN + 4;
    static_assert(CPT % 4 == 0, "CPT must be multiple of 4");
    __shared__ float sW[FIN * FOUT];
    __shared__ float sX[ROWS * XS];
    int tid = threadIdx.x;
    for (int i = tid * 4; i < FIN * FOUT; i += 1024)
        *(float4*)&sW[i] = *(const float4*)&W[i];
    int row0 = blockIdx.x * ROWS;
    for (int i = tid * 4; i < ROWS * FIN; i += 1024) {
        int r = i / FIN, k = i % FIN;
        int gr = row0 + r;
        float4 v = make_float4(0.f, 0.f, 0.f, 0.f);
        if (gr < N) v = *(const float4*)&X[(size_t)gr * FIN + k];
        *(float4*)&sX[r * XS + k] = v;
    }
    __syncthreads();
    int r  = tid / TPR;
    int cb = (tid % TPR) * 4;
    float4 acc[NG];
    #pragma unroll
    for (int g = 0; g < NG; ++g) acc[g] = make_float4(0.f, 0.f, 0.f, 0.f);
    const float* xrow = &sX[r * XS];
    for (int k = 0; k < FIN; ++k) {
        float xv = xrow[k];
        #pragma unroll
        for (int g = 0; g < NG; ++g) {
            float4 w = *(const float4*)&sW[k * FOUT + cb + g * (TPR * 4)];
            acc[g].x += xv * w.x; acc[g].y += xv * w.y;
            acc[g].z += xv * w.z; acc[g].w += xv * w.w;
        }
    }
    int gr = row0 + r;
    if (gr < N) {
        #pragma unroll
        for (int g = 0; g < NG; ++g) {
            size_t idx = (size_t)gr * FOUT + cb + g * (TPR * 4);
            if (BF16OUT) {
                ushort4 o;
                o.x = f2bf(acc[g].x); o.y = f2bf(acc[g].y);
                o.z = f2bf(acc[g].z); o.w = f2bf(acc[g].w);
                *(ushort4*)((unsigned short*)Hout + idx) = o;
            } else {
                *(float4*)((float*)Hout + idx) = acc[g];
            }
        }
    }
}

// small layer-3 GEMM: [N,64] @ [64,2] (fp32)
__global__ void gemm3_kernel(const float* __restrict__ X, const float* __restrict__ W,
                             float* __restrict__ Hout, int N) {
    int n = blockIdx.x * blockDim.x + threadIdx.x;
    if (n >= N) return;
    float a0 = 0.f, a1 = 0.f;
    const float4* xr = (const float4*)(X + (size_t)n * 64);
    #pragma unroll
    for (int k4 = 0; k4 < 16; ++k4) {
        float4 x = xr[k4];
        int k = k4 * 4;
        a0 += x.x * W[(k + 0) * 2] + x.y * W[(k + 1) * 2] + x.z * W[(k + 2) * 2] + x.w * W[(k + 3) * 2];
        a1 += x.x * W[(k + 0) * 2 + 1] + x.y * W[(k + 1) * 2 + 1] + x.z * W[(k + 2) * 2 + 1] + x.w * W[(k + 3) * 2 + 1];
    }
    Hout[n * 2 + 0] = a0;
    Hout[n * 2 + 1] = a1;
}

// ---------------------------------------------------------------- attention dots
// bf16 h input (layers 1,2)
template<int H, int C>
__global__ void attn_bf16_kernel(const unsigned short* __restrict__ Hb,
                                 const float* __restrict__ att_s, const float* __restrict__ att_d,
                                 float* __restrict__ a_src, float* __restrict__ a_dst, int N) {
    int t = blockIdx.x * blockDim.x + threadIdx.x;
    int n = t / H, h = t % H;
    if (n >= N) return;
    const uint32_t* row = (const uint32_t*)(Hb + (size_t)n * H * C + h * C);
    float as = 0.f, ad = 0.f;
    #pragma unroll
    for (int c2 = 0; c2 < C / 2; ++c2) {
        uint32_t p = row[c2];
        float v0 = bf_lo(p), v1 = bf_hi(p);
        as += v0 * att_s[h * C + c2 * 2] + v1 * att_s[h * C + c2 * 2 + 1];
        ad += v0 * att_d[h * C + c2 * 2] + v1 * att_d[h * C + c2 * 2 + 1];
    }
    a_src[n * H + h] = as;
    a_dst[n * H + h] = ad;
}

// fp32 h input (layer 3)
template<int H, int C>
__global__ void attn_kernel(const float* __restrict__ Hm, const float* __restrict__ att_s,
                            const float* __restrict__ att_d, float* __restrict__ a_src,
                            float* __restrict__ a_dst, int N) {
    int t = blockIdx.x * blockDim.x + threadIdx.x;
    int n = t / H, h = t % H;
    if (n >= N) return;
    const float* row = Hm + (size_t)n * H * C + h * C;
    float as = 0.f, ad = 0.f;
    for (int c = 0; c < C; ++c) {
        float v = row[c];
        as += v * att_s[h * C + c];
        ad += v * att_d[h * C + c];
    }
    a_src[n * H + h] = as;
    a_dst[n * H + h] = ad;
}

// ---------------------------------------------------------------- aggregation (bf16 h)
// one wave per dst node. pass1: online softmax stats (fp32). pass2: chunked
// coalesced col_src prefetch + shfl broadcast; each lane owns a bf16 pair.
template<int H, int C, bool ELU>
__global__ __launch_bounds__(256) void agg_bf16_kernel(
        const unsigned short* __restrict__ Hb, const float* __restrict__ a_src,
        const float* __restrict__ a_dst, const int* __restrict__ row_ptr,
        const int* __restrict__ col_src, const float* __restrict__ bias,
        float* __restrict__ out, int N) {
    constexpr int HC  = H * C;
    constexpr int LPE = HC / 2;       // lanes (pairs) per edge
    constexpr int EPI = 64 / LPE;     // edges per inner iteration (1 or 2)
    static_assert(64 % LPE == 0, "HC/2 must divide 64");
    int wave = (int)((blockIdx.x * blockDim.x + threadIdx.x) >> 6);
    int lane = threadIdx.x & 63;
    if (wave >= N) return;
    int n = wave;
    int start = row_ptr[n];
    int deg   = row_ptr[n + 1] - start;

    float adv[H], m[H], s[H];
    #pragma unroll
    for (int h = 0; h < H; ++h) { adv[h] = a_dst[n * H + h]; m[h] = -1e30f; s[h] = 0.f; }
    // pass 1: per-lane online max/sum per head (i==deg is the self-loop)
    for (int i = lane; i <= deg; i += 64) {
        int src = (i < deg) ? col_src[start + i] : n;
        float av[H];
        if constexpr (H == 4) {
            float4 t = *(const float4*)&a_src[src * 4];
            av[0] = t.x; av[1] = t.y; av[2] = t.z; av[3] = t.w;
        } else if constexpr (H == 2) {
            float2 t = *(const float2*)&a_src[src * 2];
            av[0] = t.x; av[1] = t.y;
        } else {
            #pragma unroll
            for (int h = 0; h < H; ++h) av[h] = a_src[src * H + h];
        }
        #pragma unroll
        for (int h = 0; h < H; ++h) {
            float e = av[h] + adv[h];
            e = (e >= 0.f) ? e : NEG_SLOPE * e;
            if (e > m[h]) {
                s[h] = s[h] * __expf(m[h] - e) + 1.f;
                m[h] = e;
            } else {
                s[h] += __expf(e - m[h]);
            }
        }
    }
    #pragma unroll
    for (int off = 32; off; off >>= 1) {
        #pragma unroll
        for (int h = 0; h < H; ++h) {
            float m2 = __shfl_xor(m[h], off);
            float s2 = __shfl_xor(s[h], off);
            float nm = fmaxf(m[h], m2);
            s[h] = s[h] * __expf(m[h] - nm) + s2 * __expf(m2 - nm);
            m[h] = nm;
        }
    }

    // pass 2: weighted gather of bf16 pairs
    int sub   = lane / LPE;           // which edge within the iteration
    int pl    = lane % LPE;           // pair index within row
    int elem0 = pl * 2;
    int hh    = elem0 / C;
    float m_h   = m[hh];
    float inv_h = 1.f / s[hh];
    float adv_h = adv[hh];
    float acc0 = 0.f, acc1 = 0.f;
    for (int base = 0; base <= deg; base += 64) {
        int myidx = base + lane;
        int msrc  = (myidx < deg) ? col_src[start + myidx] : n;  // coalesced chunk
        int cnt   = min(64, deg + 1 - base);
        #pragma unroll 2
        for (int k = 0; k < cnt; k += EPI) {
            int eidx = k + sub;
            int src  = __shfl(msrc, eidx);
            float e = a_src[src * H + hh] + adv_h;
            e = (e >= 0.f) ? e : NEG_SLOPE * e;
            float w = __expf(e - m_h) * inv_h;
            if (EPI == 2 && eidx >= cnt) w = 0.f;
            uint32_t pv = *(const uint32_t*)&Hb[(size_t)src * HC + elem0];
            acc0 += w * bf_lo(pv);
            acc1 += w * bf_hi(pv);
        }
    }
    if constexpr (EPI == 2) {
        acc0 += __shfl_xor(acc0, 32);
        acc1 += __shfl_xor(acc1, 32);
    }
    if (sub == 0) {
        float2 b = *(const float2*)&bias[elem0];
        float v0 = acc0 + b.x, v1 = acc1 + b.y;
        if (ELU) {
            v0 = (v0 > 0.f) ? v0 : __expf(v0) - 1.f;
            v1 = (v1 > 0.f) ? v1 : __expf(v1) - 1.f;
        }
        *(float2*)&out[(size_t)n * HC + elem0] = make_float2(v0, v1);
    }
}

// layer 3: H=1, C=2, fp32, fused aggregation + bias + log_softmax -> d_out
__global__ __launch_bounds__(256) void agg3_kernel(
        const float* __restrict__ Hm, const float* __restrict__ a_src,
        const float* __restrict__ a_dst, const int* __restrict__ row_ptr,
        const int* __restrict__ col_src, const float* __restrict__ bias,
        float* __restrict__ out, int N) {
    int wave = (int)((blockIdx.x * blockDim.x + threadIdx.x) >> 6);
    int lane = threadIdx.x & 63;
    if (wave >= N) return;
    int n = wave;
    int start = row_ptr[n];
    int deg   = row_ptr[n + 1] - start;
    float adv = a_dst[n];
    float m = -1e30f, s = 0.f, acc0 = 0.f, acc1 = 0.f;
    for (int i = lane; i <= deg; i += 64) {
        int src = (i < deg) ? col_src[start + i] : n;
        float e = a_src[src] + adv;
        e = (e >= 0.f) ? e : NEG_SLOPE * e;
        float h0 = Hm[src * 2], h1 = Hm[src * 2 + 1];
        if (e > m) {
            float c = __expf(m - e);
            s = s * c + 1.f; acc0 = acc0 * c + h0; acc1 = acc1 * c + h1;
            m = e;
        } else {
            float p = __expf(e - m);
            s += p; acc0 += p * h0; acc1 += p * h1;
        }
    }
    #pragma unroll
    for (int off = 32; off; off >>= 1) {
        float m2  = __shfl_xor(m, off);
        float s2  = __shfl_xor(s, off);
        float a02 = __shfl_xor(acc0, off);
        float a12 = __shfl_xor(acc1, off);
        float nm = fmaxf(m, m2);
        float c1 = __expf(m - nm), c2 = __expf(m2 - nm);
        s = s * c1 + s2 * c2; acc0 = acc0 * c1 + a02 * c2; acc1 = acc1 * c1 + a12 * c2;
        m = nm;
    }
    if (lane == 0) {
        float v0 = acc0 / s + bias[0];
        float v1 = acc1 / s + bias[1];
        float mx = fmaxf(v0, v1);
        float lse = mx + logf(__expf(v0 - mx) + __expf(v1 - mx));
        out[n * 2 + 0] = v0 - lse;
        out[n * 2 + 1] = v1 - lse;
    }
}

// ---------------------------------------------------------------- launch
extern "C" void kernel_launch(void* const* d_in, const int* in_sizes, int n_in,
                              void* d_out, int out_size, void* d_ws, size_t ws_size,
                              hipStream_t stream) {
    const float* x   = (const float*)d_in[0];
    const int*   ei  = (const int*)d_in[1];
    const float* W1  = (const float*)d_in[2];
    const float* as1 = (const float*)d_in[3];
    const float* ad1 = (const float*)d_in[4];
    const float* b1  = (const float*)d_in[5];
    const float* W2  = (const float*)d_in[6];
    const float* as2 = (const float*)d_in[7];
    const float* ad2 = (const float*)d_in[8];
    const float* b2  = (const float*)d_in[9];
    const float* W3  = (const float*)d_in[10];
    const float* as3 = (const float*)d_in[11];
    const float* ad3 = (const float*)d_in[12];
    const float* b3  = (const float*)d_in[13];
    int N = in_sizes[0] / 128;
    int E = in_sizes[1] / 2;
    const int* src = ei;
    const int* dst = ei + E;

    char* ws = (char*)d_ws;
    size_t off = 0;
    auto alloc = [&](size_t bytes) -> void* {
        void* p = ws + off;
        off = (off + bytes + 255) & ~(size_t)255;
        return p;
    };
    int*            row_ptr = (int*)alloc((size_t)(N + 1) * 4);
    int*            cursor  = (int*)alloc((size_t)N * 4);
    int*            col_src = (int*)alloc((size_t)E * 4);
    unsigned short* hb      = (unsigned short*)alloc((size_t)N * 128 * 2);  // bf16 h (layers 1,2)
    float*          obuf    = (float*)alloc((size_t)N * 128 * 4);           // fp32 aggregated
    float*          h3      = (float*)alloc((size_t)N * 2 * 4);             // fp32 layer-3 h
    float*          asrc    = (float*)alloc((size_t)N * 4 * 4);
    float*          adst    = (float*)alloc((size_t)N * 4 * 4);

    // CSR by dst
    hipMemsetAsync(cursor, 0, (size_t)N * 4, stream);
    hist_kernel<<<(E + 255) / 256, 256, 0, stream>>>(dst, cursor, E);
    scan_kernel<<<1, 1024, 0, stream>>>(cursor, row_ptr, N);
    hipMemsetAsync(cursor, 0, (size_t)N * 4, stream);
    scatter_kernel<<<(E + 255) / 256, 256, 0, stream>>>(src, dst, row_ptr, cursor, col_src, E);

    // layer 1: 128 -> 4x32 (concat), elu
    gemm_kernel<128, 128, 16, true><<<(N + 15) / 16, 256, 0, stream>>>(x, W1, hb, N);
    attn_bf16_kernel<4, 32><<<(N * 4 + 255) / 256, 256, 0, stream>>>(hb, as1, ad1, asrc, adst, N);
    agg_bf16_kernel<4, 32, true><<<(N + 3) / 4, 256, 0, stream>>>(hb, asrc, adst, row_ptr, col_src, b1, obuf, N);

    // layer 2: 128 -> 2x32 (concat), elu
    gemm_kernel<128, 64, 16, true><<<(N + 15) / 16, 256, 0, stream>>>(obuf, W2, hb, N);
    attn_bf16_kernel<2, 32><<<(N * 2 + 255) / 256, 256, 0, stream>>>(hb, as2, ad2, asrc, adst, N);
    agg_bf16_kernel<2, 32, true><<<(N + 3) / 4, 256, 0, stream>>>(hb, asrc, adst, row_ptr, col_src, b2, obuf, N);

    // layer 3: 64 -> 2, 1 head, bias, log_softmax
    gemm3_kernel<<<(N + 255) / 256, 256, 0, stream>>>(obuf, W3, h3, N);
    attn_kernel<1, 2><<<(N + 255) / 256, 256, 0, stream>>>(h3, as3, ad3, asrc, adst, N);
    agg3_kernel<<<(N + 3) / 4, 256, 0, stream>>>(h3, asrc, adst, row_ptr, col_src, b3, (float*)d_out, N);
}

// Round 3
// 425.369 us; speedup vs baseline: 1.6701x; 1.2366x over previous
//
#include <hip/hip_runtime.h>
#include <hip/hip_bf16.h>

#define NEG_SLOPE 0.2f

// ---------------------------------------------------------------- bf16 helpers
__device__ __forceinline__ float bf_lo(uint32_t u) { return __uint_as_float(u << 16); }
__device__ __forceinline__ float bf_hi(uint32_t u) { return __uint_as_float(u & 0xffff0000u); }
__device__ __forceinline__ unsigned short f2bf(float f) {
    uint32_t u = __float_as_uint(f);
    u += 0x7fffu + ((u >> 16) & 1u);   // round-to-nearest-even
    return (unsigned short)(u >> 16);
}

// ---------------------------------------------------------------- CSR build
__global__ void hist_kernel(const int* __restrict__ dst, int* __restrict__ counts, int E) {
    int e = blockIdx.x * blockDim.x + threadIdx.x;
    if (e < E) atomicAdd(&counts[dst[e]], 1);
}

// single-block exclusive scan: counts[N] -> row_ptr[N+1]
__global__ void scan_kernel(const int* __restrict__ counts, int* __restrict__ row_ptr, int N) {
    __shared__ int wsum[16];
    __shared__ int carry_s;
    int tid = threadIdx.x, lane = tid & 63, wid = tid >> 6;
    if (tid == 0) carry_s = 0;
    __syncthreads();
    for (int base = 0; base < N; base += 1024) {
        int i = base + tid;
        int v = (i < N) ? counts[i] : 0;
        int x = v;
        #pragma unroll
        for (int off = 1; off < 64; off <<= 1) {
            int t = __shfl_up(x, off);
            if (lane >= off) x += t;
        }
        if (lane == 63) wsum[wid] = x;
        __syncthreads();
        if (wid == 0 && lane < 16) {
            int w = wsum[lane];
            int inc = w;
            #pragma unroll
            for (int off = 1; off < 16; off <<= 1) {
                int t = __shfl_up(inc, off);
                if (lane >= off) inc += t;
            }
            wsum[lane] = inc - w;
        }
        __syncthreads();
        int excl = carry_s + wsum[wid] + x - v;
        if (i < N) row_ptr[i] = excl;
        __syncthreads();
        if (tid == 1023) carry_s += wsum[15] + x;
        __syncthreads();
    }
    if (threadIdx.x == 0) row_ptr[N] = carry_s;
}

__global__ void scatter_kernel(const int* __restrict__ src, const int* __restrict__ dst,
                               const int* __restrict__ row_ptr, int* __restrict__ cursor,
                               int* __restrict__ col_src, int E) {
    int e = blockIdx.x * blockDim.x + threadIdx.x;
    if (e < E) {
        int d = dst[e];
        int pos = atomicAdd(&cursor[d], 1);
        col_src[row_ptr[d] + pos] = src[e];
    }
}

// ---------------------------------------------------------------- GEMM (fp32 in, fp32 or bf16 out)
template<int FIN, int FOUT, int ROWS, bool BF16OUT>
__global__ __launch_bounds__(256) void gemm_kernel(const float* __restrict__ X,
                                                   const float* __restrict__ W,
                                                   void* __restrict__ Hout, int N) {
    constexpr int TPR = 256 / ROWS;
    constexpr int CPT = FOUT / TPR;
    constexpr int NG  = CPT / 4;
    constexpr int XS  = FIN + 4;
    static_assert(CPT % 4 == 0, "CPT must be multiple of 4");
    __shared__ float sW[FIN * FOUT];
    __shared__ float sX[ROWS * XS];
    int tid = threadIdx.x;
    for (int i = tid * 4; i < FIN * FOUT; i += 1024)
        *(float4*)&sW[i] = *(const float4*)&W[i];
    int row0 = blockIdx.x * ROWS;
    for (int i = tid * 4; i < ROWS * FIN; i += 1024) {
        int r = i / FIN, k = i % FIN;
        int gr = row0 + r;
        float4 v = make_float4(0.f, 0.f, 0.f, 0.f);
        if (gr < N) v = *(const float4*)&X[(size_t)gr * FIN + k];
        *(float4*)&sX[r * XS + k] = v;
    }
    __syncthreads();
    int r  = tid / TPR;
    int cb = (tid % TPR) * 4;
    float4 acc[NG];
    #pragma unroll
    for (int g = 0; g < NG; ++g) acc[g] = make_float4(0.f, 0.f, 0.f, 0.f);
    const float* xrow = &sX[r * XS];
    for (int k = 0; k < FIN; ++k) {
        float xv = xrow[k];
        #pragma unroll
        for (int g = 0; g < NG; ++g) {
            float4 w = *(const float4*)&sW[k * FOUT + cb + g * (TPR * 4)];
            acc[g].x += xv * w.x; acc[g].y += xv * w.y;
            acc[g].z += xv * w.z; acc[g].w += xv * w.w;
        }
    }
    int gr = row0 + r;
    if (gr < N) {
        #pragma unroll
        for (int g = 0; g < NG; ++g) {
            size_t idx = (size_t)gr * FOUT + cb + g * (TPR * 4);
            if (BF16OUT) {
                ushort4 o;
                o.x = f2bf(acc[g].x); o.y = f2bf(acc[g].y);
                o.z = f2bf(acc[g].z); o.w = f2bf(acc[g].w);
                *(ushort4*)((unsigned short*)Hout + idx) = o;
            } else {
                *(float4*)((float*)Hout + idx) = acc[g];
            }
        }
    }
}

// small layer-3 GEMM: [N,64] @ [64,2] (fp32)
__global__ void gemm3_kernel(const float* __restrict__ X, const float* __restrict__ W,
                             float* __restrict__ Hout, int N) {
    int n = blockIdx.x * blockDim.x + threadIdx.x;
    if (n >= N) return;
    float a0 = 0.f, a1 = 0.f;
    const float4* xr = (const float4*)(X + (size_t)n * 64);
    #pragma unroll
    for (int k4 = 0; k4 < 16; ++k4) {
        float4 x = xr[k4];
        int k = k4 * 4;
        a0 += x.x * W[(k + 0) * 2] + x.y * W[(k + 1) * 2] + x.z * W[(k + 2) * 2] + x.w * W[(k + 3) * 2];
        a1 += x.x * W[(k + 0) * 2 + 1] + x.y * W[(k + 1) * 2 + 1] + x.z * W[(k + 2) * 2 + 1] + x.w * W[(k + 3) * 2 + 1];
    }
    Hout[n * 2 + 0] = a0;
    Hout[n * 2 + 1] = a1;
}

// ---------------------------------------------------------------- attention dots
template<int H, int C>
__global__ void attn_bf16_kernel(const unsigned short* __restrict__ Hb,
                                 const float* __restrict__ att_s, const float* __restrict__ att_d,
                                 float* __restrict__ a_src, float* __restrict__ a_dst, int N) {
    int t = blockIdx.x * blockDim.x + threadIdx.x;
    int n = t / H, h = t % H;
    if (n >= N) return;
    const uint32_t* row = (const uint32_t*)(Hb + (size_t)n * H * C + h * C);
    float as = 0.f, ad = 0.f;
    #pragma unroll
    for (int c2 = 0; c2 < C / 2; ++c2) {
        uint32_t p = row[c2];
        float v0 = bf_lo(p), v1 = bf_hi(p);
        as += v0 * att_s[h * C + c2 * 2] + v1 * att_s[h * C + c2 * 2 + 1];
        ad += v0 * att_d[h * C + c2 * 2] + v1 * att_d[h * C + c2 * 2 + 1];
    }
    a_src[n * H + h] = as;
    a_dst[n * H + h] = ad;
}

template<int H, int C>
__global__ void attn_kernel(const float* __restrict__ Hm, const float* __restrict__ att_s,
                            const float* __restrict__ att_d, float* __restrict__ a_src,
                            float* __restrict__ a_dst, int N) {
    int t = blockIdx.x * blockDim.x + threadIdx.x;
    int n = t / H, h = t % H;
    if (n >= N) return;
    const float* row = Hm + (size_t)n * H * C + h * C;
    float as = 0.f, ad = 0.f;
    for (int c = 0; c < C; ++c) {
        float v = row[c];
        as += v * att_s[h * C + c];
        ad += v * att_d[h * C + c];
    }
    a_src[n * H + h] = as;
    a_dst[n * H + h] = ad;
}

// ---------------------------------------------------------------- fused aggregation (bf16 h)
// One wave per dst node. Single pass, no max-subtraction (shift c=max(a_dst,0)
// bounds the exp argument; softmax is shift-invariant so result is exact).
// Per 64-edge chunk: phase A (each lane computes p[] for its edge -> LDS),
// phase B (per edge: broadcast ds_read of w,src + bf16-pair gather + 2 fmac).
template<int H, int C, bool ELU>
__global__ __launch_bounds__(256) void agg_fused_kernel(
        const unsigned short* __restrict__ Hb, const float* __restrict__ a_src,
        const float* __restrict__ a_dst, const int* __restrict__ row_ptr,
        const int* __restrict__ col_src, const float* __restrict__ bias,
        float* __restrict__ out, int N) {
    constexpr int HC  = H * C;
    constexpr int LPE = HC / 2;       // lanes (pairs) per edge
    constexpr int EPI = 64 / LPE;     // edges per inner iteration (1 or 2)
    constexpr int SHIFT = (HC == 128) ? 8 : 7;   // log2(HC * sizeof(bf16))
    static_assert(HC == 128 || HC == 64, "layout");
    __shared__ float sP[4][64 * H];
    __shared__ int   sS[4][64];
    int wv   = threadIdx.x >> 6;
    int lane = threadIdx.x & 63;
    int n = (int)(blockIdx.x * 4 + wv);
    if (n >= N) return;
    int start = row_ptr[n];
    int deg   = row_ptr[n + 1] - start;

    float adv[H], cc[H], sp[H];
    #pragma unroll
    for (int h = 0; h < H; ++h) {
        adv[h] = a_dst[n * H + h];
        cc[h]  = fmaxf(adv[h], 0.f);
        sp[h]  = 0.f;
    }

    int sub = lane / LPE, pl = lane % LPE;
    int elem0 = pl * 2;
    int hh = elem0 / C;
    uint32_t boff = (uint32_t)(elem0 * 2);
    float acc0 = 0.f, acc1 = 0.f;

    for (int base = 0; base <= deg; base += 64) {
        int cnt = min(64, deg + 1 - base);
        int idx = base + lane;
        if (idx <= deg) {
            int src = (idx < deg) ? col_src[start + idx] : n;
            sS[wv][lane] = src;
            float av[H];
            if constexpr (H == 4) {
                float4 t = *(const float4*)&a_src[src * 4];
                av[0] = t.x; av[1] = t.y; av[2] = t.z; av[3] = t.w;
            } else {
                float2 t = *(const float2*)&a_src[src * 2];
                av[0] = t.x; av[1] = t.y;
            }
            #pragma unroll
            for (int h = 0; h < H; ++h) {
                float e = av[h] + adv[h];
                e = (e >= 0.f) ? e : NEG_SLOPE * e;
                float p = __expf(e - cc[h]);
                sp[h] += p;
                sP[wv][lane * H + h] = p;
            }
        }
        __threadfence_block();   // LDS writes visible before reads (same wave, lockstep)
        #pragma unroll 4
        for (int k = 0; k < cnt; k += EPI) {
            int eidx = k + sub;
            int eclm = (EPI == 2) ? min(eidx, cnt - 1) : eidx;
            float w  = sP[wv][eclm * H + hh];
            int  src = sS[wv][eclm];
            if (EPI == 2 && eidx >= cnt) w = 0.f;
            uint32_t off = ((uint32_t)src << SHIFT) + boff;
            uint32_t pv = *(const uint32_t*)((const char*)Hb + off);
            acc0 = fmaf(w, bf_lo(pv), acc0);
            acc1 = fmaf(w, bf_hi(pv), acc1);
        }
        __threadfence_block();   // reads done before next chunk overwrites
    }

    #pragma unroll
    for (int off = 32; off; off >>= 1) {
        #pragma unroll
        for (int h = 0; h < H; ++h) sp[h] += __shfl_xor(sp[h], off);
    }
    if constexpr (EPI == 2) {
        acc0 += __shfl_xor(acc0, 32);
        acc1 += __shfl_xor(acc1, 32);
    }
    if (sub == 0) {
        float inv = 1.f / sp[hh];
        float2 b = *(const float2*)&bias[elem0];
        float v0 = acc0 * inv + b.x;
        float v1 = acc1 * inv + b.y;
        if (ELU) {
            v0 = (v0 > 0.f) ? v0 : __expf(v0) - 1.f;
            v1 = (v1 > 0.f) ? v1 : __expf(v1) - 1.f;
        }
        *(float2*)&out[(size_t)n * HC + elem0] = make_float2(v0, v1);
    }
}

// layer 3: H=1, C=2, fp32, single-pass (no max-sub) + bias + log_softmax -> d_out
__global__ __launch_bounds__(256) void agg3_kernel(
        const float* __restrict__ Hm, const float* __restrict__ a_src,
        const float* __restrict__ a_dst, const int* __restrict__ row_ptr,
        const int* __restrict__ col_src, const float* __restrict__ bias,
        float* __restrict__ out, int N) {
    int wave = (int)((blockIdx.x * blockDim.x + threadIdx.x) >> 6);
    int lane = threadIdx.x & 63;
    if (wave >= N) return;
    int n = wave;
    int start = row_ptr[n];
    int deg   = row_ptr[n + 1] - start;
    float adv = a_dst[n];
    float c   = fmaxf(adv, 0.f);
    float s = 0.f, acc0 = 0.f, acc1 = 0.f;
    for (int i = lane; i <= deg; i += 64) {
        int src = (i < deg) ? col_src[start + i] : n;
        float e = a_src[src] + adv;
        e = (e >= 0.f) ? e : NEG_SLOPE * e;
        float p = __expf(e - c);
        float2 hv = *(const float2*)&Hm[src * 2];
        s += p;
        acc0 = fmaf(p, hv.x, acc0);
        acc1 = fmaf(p, hv.y, acc1);
    }
    #pragma unroll
    for (int off = 32; off; off >>= 1) {
        s    += __shfl_xor(s, off);
        acc0 += __shfl_xor(acc0, off);
        acc1 += __shfl_xor(acc1, off);
    }
    if (lane == 0) {
        float v0 = acc0 / s + bias[0];
        float v1 = acc1 / s + bias[1];
        float mx = fmaxf(v0, v1);
        float lse = mx + logf(__expf(v0 - mx) + __expf(v1 - mx));
        out[n * 2 + 0] = v0 - lse;
        out[n * 2 + 1] = v1 - lse;
    }
}

// ---------------------------------------------------------------- launch
extern "C" void kernel_launch(void* const* d_in, const int* in_sizes, int n_in,
                              void* d_out, int out_size, void* d_ws, size_t ws_size,
                              hipStream_t stream) {
    const float* x   = (const float*)d_in[0];
    const int*   ei  = (const int*)d_in[1];
    const float* W1  = (const float*)d_in[2];
    const float* as1 = (const float*)d_in[3];
    const float* ad1 = (const float*)d_in[4];
    const float* b1  = (const float*)d_in[5];
    const float* W2  = (const float*)d_in[6];
    const float* as2 = (const float*)d_in[7];
    const float* ad2 = (const float*)d_in[8];
    const float* b2  = (const float*)d_in[9];
    const float* W3  = (const float*)d_in[10];
    const float* as3 = (const float*)d_in[11];
    const float* ad3 = (const float*)d_in[12];
    const float* b3  = (const float*)d_in[13];
    int N = in_sizes[0] / 128;
    int E = in_sizes[1] / 2;
    const int* src = ei;
    const int* dst = ei + E;

    char* ws = (char*)d_ws;
    size_t off = 0;
    auto alloc = [&](size_t bytes) -> void* {
        void* p = ws + off;
        off = (off + bytes + 255) & ~(size_t)255;
        return p;
    };
    int*            row_ptr = (int*)alloc((size_t)(N + 1) * 4);
    int*            cursor  = (int*)alloc((size_t)N * 4);
    int*            col_src = (int*)alloc((size_t)E * 4);
    unsigned short* hb      = (unsigned short*)alloc((size_t)N * 128 * 2);
    float*          obuf    = (float*)alloc((size_t)N * 128 * 4);
    float*          h3      = (float*)alloc((size_t)N * 2 * 4);
    float*          asrc    = (float*)alloc((size_t)N * 4 * 4);
    float*          adst    = (float*)alloc((size_t)N * 4 * 4);

    // CSR by dst
    hipMemsetAsync(cursor, 0, (size_t)N * 4, stream);
    hist_kernel<<<(E + 255) / 256, 256, 0, stream>>>(dst, cursor, E);
    scan_kernel<<<1, 1024, 0, stream>>>(cursor, row_ptr, N);
    hipMemsetAsync(cursor, 0, (size_t)N * 4, stream);
    scatter_kernel<<<(E + 255) / 256, 256, 0, stream>>>(src, dst, row_ptr, cursor, col_src, E);

    // layer 1: 128 -> 4x32 (concat), elu
    gemm_kernel<128, 128, 16, true><<<(N + 15) / 16, 256, 0, stream>>>(x, W1, hb, N);
    attn_bf16_kernel<4, 32><<<(N * 4 + 255) / 256, 256, 0, stream>>>(hb, as1, ad1, asrc, adst, N);
    agg_fused_kernel<4, 32, true><<<(N + 3) / 4, 256, 0, stream>>>(hb, asrc, adst, row_ptr, col_src, b1, obuf, N);

    // layer 2: 128 -> 2x32 (concat), elu
    gemm_kernel<128, 64, 16, true><<<(N + 15) / 16, 256, 0, stream>>>(obuf, W2, hb, N);
    attn_bf16_kernel<2, 32><<<(N * 2 + 255) / 256, 256, 0, stream>>>(hb, as2, ad2, asrc, adst, N);
    agg_fused_kernel<2, 32, true><<<(N + 3) / 4, 256, 0, stream>>>(hb, asrc, adst, row_ptr, col_src, b2, obuf, N);

    // layer 3: 64 -> 2, 1 head, bias, log_softmax
    gemm3_kernel<<<(N + 255) / 256, 256, 0, stream>>>(obuf, W3, h3, N);
    attn_kernel<1, 2><<<(N + 255) / 256, 256, 0, stream>>>(h3, as3, ad3, asrc, adst, N);
    agg3_kernel<<<(N + 3) / 4, 256, 0, stream>>>(h3, asrc, adst, row_ptr, col_src, b3, (float*)d_out, N);
}